// Round 16
// baseline (123.074 us; speedup 1.0000x reference)
//
#include <hip/hip_runtime.h>
#include <hip/hip_bf16.h>

// S=8192, D_IN=512, D_OUT=64. O = softmax(tril(QK^T)/8) @ V.
// Round 16: proj restructured to read x ONCE (was 3x -> 48MB w/ L3 re-reads).
// 256 blocks x 12 waves: x-tile (32x512 bf16, 32KB, swizzled) staged once,
// one barrier; each wave owns (mat, 16-col) tile, W B-frags in registers
// (fp32->bf16 in-reg, W is L2-resident). attn + reduce byte-exact R15.

typedef __attribute__((ext_vector_type(8))) short short8;   // 8 bf16 MFMA A/B frag
typedef __attribute__((ext_vector_type(4))) float f32x4;    // MFMA C/D frag
typedef __attribute__((ext_vector_type(4))) float f4v;
typedef __attribute__((ext_vector_type(2))) unsigned int u32x2;

__device__ inline unsigned int pk2(float a, float b) {
    union { __hip_bfloat162 h; unsigned int u; } v;
    v.h = __float22bfloat162_rn(make_float2(a, b));
    return v.u;
}
__device__ inline void gload_lds16(const void* g, void* l) {
    __builtin_amdgcn_global_load_lds(
        (const __attribute__((address_space(1))) unsigned int*)g,
        (__attribute__((address_space(3))) unsigned int*)l, 16, 0, 0);
}

// Q-blocks of 256 rows (qb in [0,32)), parts of 512 cols. np(qb) = (qb>>1)+1.
// qb = 2a+b: base(qb) = a*a + a + b*(a+1). Total slots = 272.
__device__ inline int part_base(int qb) {
    int a = qb >> 1;
    return a * a + a + (qb & 1) * (a + 1);
}

// ---------------- QKV projection: x read once, W in registers ----------------
// grid 256, 768 thr (12 waves). Block: 32 x-rows. Wave w: mat=w>>2 (Q/K/V),
// n-tile=w&3 (16 cols). x-tile [32][512] bf16 in LDS (chunk^=(row&7)).
__global__ __launch_bounds__(768) void proj_kernel(const float* __restrict__ x,
                                                   const float* __restrict__ wq,
                                                   const float* __restrict__ wk,
                                                   const float* __restrict__ wv,
                                                   unsigned short* __restrict__ qb,
                                                   unsigned short* __restrict__ kb,
                                                   unsigned short* __restrict__ vt) {
    __shared__ unsigned short lds_x[32 * 512];   // 32 KB
    const int tid = threadIdx.x;
    const int wave = tid >> 6, lane = tid & 63;
    const int l16 = lane & 15, quad = lane >> 4;
    const int r0 = blockIdx.x * 32;

    // stage + convert x-tile: 2048 chunks of 8 bf16 (rows 64 chunks each)
#pragma unroll
    for (int j = 0; j < 3; ++j) {
        const int idx = j * 768 + tid;
        if (idx < 2048) {
            const int row = idx >> 6;
            const int gc = (idx & 63) ^ (row & 7);
            const float* src = x + (r0 + row) * 512 + gc * 8;
            f4v v0 = *(const f4v*)src;
            f4v v1 = *(const f4v*)(src + 4);
            union { short8 s8; unsigned int u[4]; } pv;
            pv.u[0] = pk2(v0.x, v0.y); pv.u[1] = pk2(v0.z, v0.w);
            pv.u[2] = pk2(v1.x, v1.y); pv.u[3] = pk2(v1.z, v1.w);
            *(short8*)(lds_x + idx * 8) = pv.s8;
        }
    }

    // W B-frags in registers (concurrent with staging): wave's 16 cols, all K.
    const int mat = wave >> 2;                   // 0..2
    const int nt = wave & 3;                     // 0..3
    const float* wm = (mat == 0) ? wq : ((mat == 1) ? wk : wv);
    const float* wr = wm + (nt * 16 + l16) * 512 + quad * 8;
    short8 wf[16];
#pragma unroll
    for (int kc = 0; kc < 16; ++kc) {
        f4v v0 = *(const f4v*)(wr + kc * 32);
        f4v v1 = *(const f4v*)(wr + kc * 32 + 4);
        union { short8 s8; unsigned int u[4]; } pv;
        pv.u[0] = pk2(v0.x, v0.y); pv.u[1] = pk2(v0.z, v0.w);
        pv.u[2] = pk2(v1.x, v1.y); pv.u[3] = pk2(v1.z, v1.w);
        wf[kc] = pv.s8;
    }
    __syncthreads();                             // single barrier

    // compute: 2 m-tiles x 16 kc
    f32x4 acc[2] = {};
#pragma unroll
    for (int kc = 0; kc < 16; ++kc) {
#pragma unroll
        for (int mt = 0; mt < 2; ++mt) {
            const int row = mt * 16 + l16;
            short8 a = *(const short8*)(lds_x + row * 512 +
                                        (((kc * 4 + quad) ^ (l16 & 7)) * 8));
            acc[mt] = __builtin_amdgcn_mfma_f32_16x16x32_bf16(a, wf[kc], acc[mt], 0, 0, 0);
        }
    }

    const float scale = (mat == 0) ? 0.125f : 1.0f;   // fold 1/sqrt(d_k) into Q
    const int col = nt * 16 + l16;               // within mat, 0..63
#pragma unroll
    for (int mt = 0; mt < 2; ++mt)
#pragma unroll
        for (int r = 0; r < 4; ++r) {
            const int row = r0 + mt * 16 + quad * 4 + r;  // C/D: row=(lane>>4)*4+reg, col=lane&15
            union { __hip_bfloat16 h; unsigned short u; } hv;
            hv.h = __float2bfloat16(acc[mt][r] * scale);
            if (mat == 0)       qb[row * 64 + col] = hv.u;
            else if (mat == 1)  kb[row * 64 + col] = hv.u;
            else                vt[col * 8192 + row] = hv.u;   // V^T [64][8192]
        }
}

// ---------------- staged split-K flash attention, 256-row Q-blocks (R15 byte-exact) ----------------
// grid (16, 32), 512 thr (8 waves). blockIdx.y = qb (256 rows), x = part (512 cols).
__global__ __launch_bounds__(512) void attn_kernel(const unsigned short* __restrict__ qbuf,
                                                   const unsigned short* __restrict__ kbuf,
                                                   const unsigned short* __restrict__ vt,
                                                   float* __restrict__ O_part,
                                                   float* __restrict__ l_part) {
    const int qb_i = blockIdx.y;
    const int part = blockIdx.x;
    const int a = qb_i >> 1;
    if (part > a) return;                         // np = a+1; block-uniform exit

    __shared__ unsigned short lds_k[64 * 64];     // [row][64], chunk^=(row&7)  8KB
    __shared__ unsigned short lds_v[64 * 64];     // V^T tile [dim][64]         8KB
    __shared__ unsigned short lds_p[8][32 * 72];  // per-wave P, stride 72      36KB

    const int tid = threadIdx.x;
    const int wave = tid >> 6, lane = tid & 63;
    const int l16 = lane & 15, quad = lane >> 4;
    const int q0 = qb_i * 256;
    const int q0w = q0 + wave * 32;
    const int c0 = part * 512;
    const int cend = min(c0 + 512, q0 + 256);     // 64-aligned
    const int ntiles = (cend - c0) >> 6;          // 4 or 8
    unsigned short* lp = lds_p[wave];

    f32x4 o[2][4] = {};
    float ls[2] = {0.f, 0.f};

    short8 qf[2][2];
#pragma unroll
    for (int cg = 0; cg < 2; ++cg)
#pragma unroll
        for (int kg = 0; kg < 2; ++kg)
            qf[cg][kg] = *(const short8*)(qbuf + (q0w + cg * 16 + l16) * 64 + kg * 32 + quad * 8);

    const int sidx = tid;
    const int srow = sidx >> 3;
    const int scc = (sidx & 7) ^ (srow & 7);

    for (int it = 0; it < ntiles; ++it) {
        const int kc0 = c0 + it * 64;
        gload_lds16(kbuf + (kc0 + srow) * 64 + scc * 8, lds_k + sidx * 8);
        gload_lds16(vt + srow * 8192 + kc0 + scc * 8,   lds_v + sidx * 8);
        __syncthreads();

        if (kc0 <= q0w + 31) {                    // wave-uniform compute guard
            short8 af[4][2], vf[4][2];
#pragma unroll
            for (int rg = 0; rg < 4; ++rg)
#pragma unroll
                for (int kg = 0; kg < 2; ++kg)
                    af[rg][kg] = *(const short8*)(lds_k + (rg * 16 + l16) * 64 +
                                                  (((kg * 4 + quad) ^ (l16 & 7)) * 8));
#pragma unroll
            for (int ng = 0; ng < 4; ++ng)
#pragma unroll
                for (int kg = 0; kg < 2; ++kg)
                    vf[ng][kg] = *(const short8*)(lds_v + (ng * 16 + l16) * 64 +
                                                  (((kg * 4 + quad) ^ (l16 & 7)) * 8));

            // S^T = K Q^T: row=K-col kc0+rg*16+quad*4+r, col=Q-row q0w+cg*16+l16
            f32x4 st[4][2];
#pragma unroll
            for (int rg = 0; rg < 4; ++rg)
#pragma unroll
                for (int cg = 0; cg < 2; ++cg) {
                    f32x4 z = {};
                    z          = __builtin_amdgcn_mfma_f32_16x16x32_bf16(af[rg][0], qf[cg][0], z, 0, 0, 0);
                    st[rg][cg] = __builtin_amdgcn_mfma_f32_16x16x32_bf16(af[rg][1], qf[cg][1], z, 0, 0, 0);
                }

            if (kc0 + 63 > q0w) {                 // diagonal tiles only
#pragma unroll
                for (int rg = 0; rg < 4; ++rg)
#pragma unroll
                    for (int cg = 0; cg < 2; ++cg)
#pragma unroll
                        for (int r = 0; r < 4; ++r) {
                            const int kcol = kc0 + rg * 16 + quad * 4 + r;
                            const int qrow = q0w + cg * 16 + l16;
                            if (kcol > qrow) st[rg][cg][r] = -3.0e38f;
                        }
            }

            // p = exp(s), no max subtraction (r3-validated)
#pragma unroll
            for (int rg = 0; rg < 4; ++rg)
#pragma unroll
                for (int cg = 0; cg < 2; ++cg)
#pragma unroll
                    for (int r = 0; r < 4; ++r) {
                        const float p = __expf(st[rg][cg][r]);
                        st[rg][cg][r] = p;
                        ls[cg] += p;
                    }

            // P -> per-wave LDS, stride 72 (wave-synchronous)
#pragma unroll
            for (int rg = 0; rg < 4; ++rg)
#pragma unroll
                for (int cg = 0; cg < 2; ++cg) {
                    u32x2 w;
                    w.x = pk2(st[rg][cg][0], st[rg][cg][1]);
                    w.y = pk2(st[rg][cg][2], st[rg][cg][3]);
                    *(u32x2*)(lp + (cg * 16 + l16) * 72 + rg * 16 + quad * 4) = w;
                }
            asm volatile("s_waitcnt lgkmcnt(0)" ::: "memory");
            short8 pa[2][2];
#pragma unroll
            for (int mg = 0; mg < 2; ++mg)
#pragma unroll
                for (int kg = 0; kg < 2; ++kg)
                    pa[mg][kg] = *(const short8*)(lp + (mg * 16 + l16) * 72 + kg * 32 + quad * 8);

#pragma unroll
            for (int mg = 0; mg < 2; ++mg)
#pragma unroll
                for (int ng = 0; ng < 4; ++ng) {
                    o[mg][ng] = __builtin_amdgcn_mfma_f32_16x16x32_bf16(pa[mg][0], vf[ng][0], o[mg][ng], 0, 0, 0);
                    o[mg][ng] = __builtin_amdgcn_mfma_f32_16x16x32_bf16(pa[mg][1], vf[ng][1], o[mg][ng], 0, 0, 0);
                }
        }
        __syncthreads();
    }

#pragma unroll
    for (int cg = 0; cg < 2; ++cg) {
        ls[cg] += __shfl_xor(ls[cg], 16, 64);
        ls[cg] += __shfl_xor(ls[cg], 32, 64);
    }

    const int slot = part_base(qb_i) + part;
    float* Op = O_part + (size_t)slot * 16384;    // 256 rows x 64 cols
#pragma unroll
    for (int mg = 0; mg < 2; ++mg)
#pragma unroll
        for (int ng = 0; ng < 4; ++ng)
#pragma unroll
            for (int r = 0; r < 4; ++r)
                __builtin_nontemporal_store(o[mg][ng][r],
                    Op + (wave * 32 + mg * 16 + quad * 4 + r) * 64 + ng * 16 + l16);
    if (quad == 0) {
#pragma unroll
        for (int cg = 0; cg < 2; ++cg)
            __builtin_nontemporal_store(ls[cg],
                l_part + slot * 256 + wave * 32 + cg * 16 + l16);
    }
}

// ---------------- combine: parallel sum, latency-hidden (R15 byte-exact) ----------------
__global__ __launch_bounds__(256) void attn_reduce_kernel(const float* __restrict__ O_part,
                                                          const float* __restrict__ l_part,
                                                          float* __restrict__ out) {
    __shared__ float Ls[16];
    const int qb_i = blockIdx.y;
    const int c = blockIdx.x;
    const int t = threadIdx.x;
    const int np = (qb_i >> 1) + 1;
    const int base = part_base(qb_i);

    if (t < 16) {
        float s = 0.0f;
        for (int p = 0; p < np; ++p)
            s += l_part[(base + p) * 256 + c * 16 + t];
        Ls[t] = s;
    }
    __syncthreads();

    const int e = c * 1024 + t * 4;               // element within slot / out tile
    const float* src = O_part + (size_t)base * 16384 + e;

    f4v a0 = {0.f, 0.f, 0.f, 0.f}, a1 = a0, a2 = a0, a3 = a0;
    int p = 0;
    for (; p + 4 <= np; p += 4) {
        a0 += *(const f4v*)(src + (size_t)(p    ) * 16384);
        a1 += *(const f4v*)(src + (size_t)(p + 1) * 16384);
        a2 += *(const f4v*)(src + (size_t)(p + 2) * 16384);
        a3 += *(const f4v*)(src + (size_t)(p + 3) * 16384);
    }
    for (; p < np; ++p)
        a0 += *(const f4v*)(src + (size_t)p * 16384);

    f4v acc = (a0 + a1) + (a2 + a3);
    acc *= (1.0f / Ls[t >> 4]);
    *(f4v*)(out + (size_t)qb_i * 16384 + e) = acc;
}

extern "C" void kernel_launch(void* const* d_in, const int* in_sizes, int n_in,
                              void* d_out, int out_size, void* d_ws, size_t ws_size,
                              hipStream_t stream) {
    const float* x  = (const float*)d_in[0];
    const float* wq = (const float*)d_in[1];
    const float* wk = (const float*)d_in[2];
    const float* wv = (const float*)d_in[3];
    float* out = (float*)d_out;

    char* ws = (char*)d_ws;
    unsigned short* qb = (unsigned short*)(ws);               // 1,048,576 B
    unsigned short* kb = (unsigned short*)(ws + 1048576);     // 1,048,576 B
    unsigned short* vt = (unsigned short*)(ws + 2097152);     // 1,048,576 B (V^T [64][8192])
    float* O_part = (float*)(ws + 3145728);                   // 272*16384*4 = 17,825,792 B
    float* l_part = (float*)(ws + 20971520);                  // 272*256*4 = 278,528 B
    // total ws: 21,250,048 B

    proj_kernel<<<256, 768, 0, stream>>>(x, wq, wk, wv, qb, kb, vt);
    attn_kernel<<<dim3(16, 32), 512, 0, stream>>>(qb, kb, vt, O_part, l_part);
    attn_reduce_kernel<<<dim3(16, 32), 256, 0, stream>>>(O_part, l_part, out);
}

// Round 17
// 120.994 us; speedup vs baseline: 1.0172x; 1.0172x over previous
//
#include <hip/hip_runtime.h>
#include <hip/hip_bf16.h>

// S=8192, D_IN=512, D_OUT=64. O = softmax(tril(QK^T)/8) @ V.
// Round 17: R15 base (best, 119.2us). One change: proj's V^T epilogue no
// longer scatters 2B stores at 16KB lane stride (8x write amplification,
// partial-line RMW). The 64x64 V D-tile is transposed through LDS (stride 68)
// and stored as contiguous 128B rows of V^T, nontemporal. attn+reduce R15-exact.

typedef __attribute__((ext_vector_type(8))) short short8;   // 8 bf16 MFMA A/B frag
typedef __attribute__((ext_vector_type(4))) float f32x4;    // MFMA C/D frag
typedef __attribute__((ext_vector_type(4))) float f4v;
typedef __attribute__((ext_vector_type(2))) unsigned int u32x2;

__device__ inline unsigned int pk2(float a, float b) {
    union { __hip_bfloat162 h; unsigned int u; } v;
    v.h = __float22bfloat162_rn(make_float2(a, b));
    return v.u;
}
__device__ inline void gload_lds16(const void* g, void* l) {
    __builtin_amdgcn_global_load_lds(
        (const __attribute__((address_space(1))) unsigned int*)g,
        (__attribute__((address_space(3))) unsigned int*)l, 16, 0, 0);
}

// Q-blocks of 256 rows (qb in [0,32)), parts of 512 cols. np(qb) = (qb>>1)+1.
// qb = 2a+b: base(qb) = a*a + a + b*(a+1). Total slots = 272.
__device__ inline int part_base(int qb) {
    int a = qb >> 1;
    return a * a + a + (qb & 1) * (a + 1);
}

// ---------------- QKV projection (R15 base; V^T via LDS transpose) ----------------
// grid (128, 3): x = 64-row block, y = mat. 4 waves, 16 rows each.
__global__ __launch_bounds__(256) void proj_kernel(const float* __restrict__ x,
                                                   const float* __restrict__ wq,
                                                   const float* __restrict__ wk,
                                                   const float* __restrict__ wv,
                                                   unsigned short* __restrict__ qb,
                                                   unsigned short* __restrict__ kb,
                                                   unsigned short* __restrict__ vt) {
    __shared__ unsigned short lds_w[64 * 512];   // 64KB bf16 W_mat, chunk^=(row&7)
    const int tid = threadIdx.x;
    const int wave = tid >> 6, lane = tid & 63;
    const int l16 = lane & 15, quad = lane >> 4;
    const int mat = blockIdx.y;
    const int rblk = blockIdx.x * 64;
    const int r0 = rblk + wave * 16;
    const float* wm = (mat == 0) ? wq : ((mat == 1) ? wk : wv);

    // stage + convert W_mat: 4096 chunks of 8 bf16
#pragma unroll
    for (int j = 0; j < 16; ++j) {
        const int idx = j * 256 + tid;
        const int row = idx >> 6;
        const int gc = (idx & 63) ^ (row & 7);
        f4v v0 = *(const f4v*)(wm + row * 512 + gc * 8);
        f4v v1 = *(const f4v*)(wm + row * 512 + gc * 8 + 4);
        union { short8 s8; unsigned int u[4]; } pv;
        pv.u[0] = pk2(v0.x, v0.y); pv.u[1] = pk2(v0.z, v0.w);
        pv.u[2] = pk2(v1.x, v1.y); pv.u[3] = pk2(v1.z, v1.w);
        *(short8*)(lds_w + idx * 8) = pv.s8;
    }
    __syncthreads();

    const float* xr = x + (r0 + l16) * 512 + quad * 8;
    f32x4 acc[4] = {};
    for (int kc = 0; kc < 16; ++kc) {
        f4v a0 = *(const f4v*)(xr + kc * 32);
        f4v a1 = *(const f4v*)(xr + kc * 32 + 4);
        union { short8 s8; unsigned int u[4]; } av;
        av.u[0] = pk2(a0.x, a0.y); av.u[1] = pk2(a0.z, a0.w);
        av.u[2] = pk2(a1.x, a1.y); av.u[3] = pk2(a1.z, a1.w);
#pragma unroll
        for (int c = 0; c < 4; ++c) {
            short8 b = *(const short8*)(lds_w + (c * 16 + l16) * 512 +
                                        (((kc * 4 + quad) ^ (l16 & 7)) * 8));
            acc[c] = __builtin_amdgcn_mfma_f32_16x16x32_bf16(av.s8, b, acc[c], 0, 0, 0);
        }
    }

    if (mat != 2) {
        const float scale = (mat == 0) ? 0.125f : 1.0f;   // fold 1/sqrt(d_k) into Q
#pragma unroll
        for (int c = 0; c < 4; ++c)
#pragma unroll
            for (int r = 0; r < 4; ++r) {
                const int row = r0 + quad * 4 + r;   // C/D: row=(lane>>4)*4+reg, col=lane&15
                const int col = c * 16 + l16;
                union { __hip_bfloat16 h; unsigned short u; } hv;
                hv.h = __float2bfloat16(acc[c][r] * scale);
                if (mat == 0) qb[row * 64 + col] = hv.u;
                else          kb[row * 64 + col] = hv.u;
            }
    } else {
        // V: transpose 64x64 D-tile in LDS (stride 68: 8B-aligned, bank-rotating),
        // then store V^T rows as contiguous 128B runs (nontemporal).
        __syncthreads();                              // done reading lds_w
        unsigned short* lds_t = lds_w;                // reuse: 64 * 68 * 2B = 8.5KB
#pragma unroll
        for (int c = 0; c < 4; ++c)
#pragma unroll
            for (int r = 0; r < 4; ++r) {
                const int row_l = wave * 16 + quad * 4 + r;   // 0..63 local row
                const int col = c * 16 + l16;                  // 0..63 out dim
                union { __hip_bfloat16 h; unsigned short u; } hv;
                hv.h = __float2bfloat16(acc[c][r]);
                lds_t[col * 68 + row_l] = hv.u;
            }
        __syncthreads();
        // readback: 1024 u32x2 units (4 elems each); d = dim, u = 4-elem unit
#pragma unroll
        for (int j = 0; j < 4; ++j) {
            const int idx = j * 256 + tid;
            const int d = idx >> 4;
            const int u = idx & 15;
            u32x2 v = *(const u32x2*)(lds_t + d * 68 + u * 4);
            __builtin_nontemporal_store(v, (u32x2*)(vt + d * 8192 + rblk + u * 4));
        }
    }
}

// ---------------- staged split-K flash attention, 256-row Q-blocks (R15 byte-exact) ----------------
// grid (16, 32), 512 thr (8 waves). blockIdx.y = qb (256 rows), x = part (512 cols).
__global__ __launch_bounds__(512) void attn_kernel(const unsigned short* __restrict__ qbuf,
                                                   const unsigned short* __restrict__ kbuf,
                                                   const unsigned short* __restrict__ vt,
                                                   float* __restrict__ O_part,
                                                   float* __restrict__ l_part) {
    const int qb_i = blockIdx.y;
    const int part = blockIdx.x;
    const int a = qb_i >> 1;
    if (part > a) return;                         // np = a+1; block-uniform exit

    __shared__ unsigned short lds_k[64 * 64];     // [row][64], chunk^=(row&7)  8KB
    __shared__ unsigned short lds_v[64 * 64];     // V^T tile [dim][64]         8KB
    __shared__ unsigned short lds_p[8][32 * 72];  // per-wave P, stride 72      36KB

    const int tid = threadIdx.x;
    const int wave = tid >> 6, lane = tid & 63;
    const int l16 = lane & 15, quad = lane >> 4;
    const int q0 = qb_i * 256;
    const int q0w = q0 + wave * 32;
    const int c0 = part * 512;
    const int cend = min(c0 + 512, q0 + 256);     // 64-aligned
    const int ntiles = (cend - c0) >> 6;          // 4 or 8
    unsigned short* lp = lds_p[wave];

    f32x4 o[2][4] = {};
    float ls[2] = {0.f, 0.f};

    short8 qf[2][2];
#pragma unroll
    for (int cg = 0; cg < 2; ++cg)
#pragma unroll
        for (int kg = 0; kg < 2; ++kg)
            qf[cg][kg] = *(const short8*)(qbuf + (q0w + cg * 16 + l16) * 64 + kg * 32 + quad * 8);

    const int sidx = tid;
    const int srow = sidx >> 3;
    const int scc = (sidx & 7) ^ (srow & 7);

    for (int it = 0; it < ntiles; ++it) {
        const int kc0 = c0 + it * 64;
        gload_lds16(kbuf + (kc0 + srow) * 64 + scc * 8, lds_k + sidx * 8);
        gload_lds16(vt + srow * 8192 + kc0 + scc * 8,   lds_v + sidx * 8);
        __syncthreads();

        if (kc0 <= q0w + 31) {                    // wave-uniform compute guard
            short8 af[4][2], vf[4][2];
#pragma unroll
            for (int rg = 0; rg < 4; ++rg)
#pragma unroll
                for (int kg = 0; kg < 2; ++kg)
                    af[rg][kg] = *(const short8*)(lds_k + (rg * 16 + l16) * 64 +
                                                  (((kg * 4 + quad) ^ (l16 & 7)) * 8));
#pragma unroll
            for (int ng = 0; ng < 4; ++ng)
#pragma unroll
                for (int kg = 0; kg < 2; ++kg)
                    vf[ng][kg] = *(const short8*)(lds_v + (ng * 16 + l16) * 64 +
                                                  (((kg * 4 + quad) ^ (l16 & 7)) * 8));

            // S^T = K Q^T: row=K-col kc0+rg*16+quad*4+r, col=Q-row q0w+cg*16+l16
            f32x4 st[4][2];
#pragma unroll
            for (int rg = 0; rg < 4; ++rg)
#pragma unroll
                for (int cg = 0; cg < 2; ++cg) {
                    f32x4 z = {};
                    z          = __builtin_amdgcn_mfma_f32_16x16x32_bf16(af[rg][0], qf[cg][0], z, 0, 0, 0);
                    st[rg][cg] = __builtin_amdgcn_mfma_f32_16x16x32_bf16(af[rg][1], qf[cg][1], z, 0, 0, 0);
                }

            if (kc0 + 63 > q0w) {                 // diagonal tiles only
#pragma unroll
                for (int rg = 0; rg < 4; ++rg)
#pragma unroll
                    for (int cg = 0; cg < 2; ++cg)
#pragma unroll
                        for (int r = 0; r < 4; ++r) {
                            const int kcol = kc0 + rg * 16 + quad * 4 + r;
                            const int qrow = q0w + cg * 16 + l16;
                            if (kcol > qrow) st[rg][cg][r] = -3.0e38f;
                        }
            }

            // p = exp(s), no max subtraction (r3-validated)
#pragma unroll
            for (int rg = 0; rg < 4; ++rg)
#pragma unroll
                for (int cg = 0; cg < 2; ++cg)
#pragma unroll
                    for (int r = 0; r < 4; ++r) {
                        const float p = __expf(st[rg][cg][r]);
                        st[rg][cg][r] = p;
                        ls[cg] += p;
                    }

            // P -> per-wave LDS, stride 72 (wave-synchronous)
#pragma unroll
            for (int rg = 0; rg < 4; ++rg)
#pragma unroll
                for (int cg = 0; cg < 2; ++cg) {
                    u32x2 w;
                    w.x = pk2(st[rg][cg][0], st[rg][cg][1]);
                    w.y = pk2(st[rg][cg][2], st[rg][cg][3]);
                    *(u32x2*)(lp + (cg * 16 + l16) * 72 + rg * 16 + quad * 4) = w;
                }
            asm volatile("s_waitcnt lgkmcnt(0)" ::: "memory");
            short8 pa[2][2];
#pragma unroll
            for (int mg = 0; mg < 2; ++mg)
#pragma unroll
                for (int kg = 0; kg < 2; ++kg)
                    pa[mg][kg] = *(const short8*)(lp + (mg * 16 + l16) * 72 + kg * 32 + quad * 8);

#pragma unroll
            for (int mg = 0; mg < 2; ++mg)
#pragma unroll
                for (int ng = 0; ng < 4; ++ng) {
                    o[mg][ng] = __builtin_amdgcn_mfma_f32_16x16x32_bf16(pa[mg][0], vf[ng][0], o[mg][ng], 0, 0, 0);
                    o[mg][ng] = __builtin_amdgcn_mfma_f32_16x16x32_bf16(pa[mg][1], vf[ng][1], o[mg][ng], 0, 0, 0);
                }
        }
        __syncthreads();
    }

#pragma unroll
    for (int cg = 0; cg < 2; ++cg) {
        ls[cg] += __shfl_xor(ls[cg], 16, 64);
        ls[cg] += __shfl_xor(ls[cg], 32, 64);
    }

    const int slot = part_base(qb_i) + part;
    float* Op = O_part + (size_t)slot * 16384;    // 256 rows x 64 cols
#pragma unroll
    for (int mg = 0; mg < 2; ++mg)
#pragma unroll
        for (int ng = 0; ng < 4; ++ng)
#pragma unroll
            for (int r = 0; r < 4; ++r)
                __builtin_nontemporal_store(o[mg][ng][r],
                    Op + (wave * 32 + mg * 16 + quad * 4 + r) * 64 + ng * 16 + l16);
    if (quad == 0) {
#pragma unroll
        for (int cg = 0; cg < 2; ++cg)
            __builtin_nontemporal_store(ls[cg],
                l_part + slot * 256 + wave * 32 + cg * 16 + l16);
    }
}

// ---------------- combine: parallel sum, latency-hidden (R15 byte-exact) ----------------
__global__ __launch_bounds__(256) void attn_reduce_kernel(const float* __restrict__ O_part,
                                                          const float* __restrict__ l_part,
                                                          float* __restrict__ out) {
    __shared__ float Ls[16];
    const int qb_i = blockIdx.y;
    const int c = blockIdx.x;
    const int t = threadIdx.x;
    const int np = (qb_i >> 1) + 1;
    const int base = part_base(qb_i);

    if (t < 16) {
        float s = 0.0f;
        for (int p = 0; p < np; ++p)
            s += l_part[(base + p) * 256 + c * 16 + t];
        Ls[t] = s;
    }
    __syncthreads();

    const int e = c * 1024 + t * 4;               // element within slot / out tile
    const float* src = O_part + (size_t)base * 16384 + e;

    f4v a0 = {0.f, 0.f, 0.f, 0.f}, a1 = a0, a2 = a0, a3 = a0;
    int p = 0;
    for (; p + 4 <= np; p += 4) {
        a0 += *(const f4v*)(src + (size_t)(p    ) * 16384);
        a1 += *(const f4v*)(src + (size_t)(p + 1) * 16384);
        a2 += *(const f4v*)(src + (size_t)(p + 2) * 16384);
        a3 += *(const f4v*)(src + (size_t)(p + 3) * 16384);
    }
    for (; p < np; ++p)
        a0 += *(const f4v*)(src + (size_t)p * 16384);

    f4v acc = (a0 + a1) + (a2 + a3);
    acc *= (1.0f / Ls[t >> 4]);
    *(f4v*)(out + (size_t)qb_i * 16384 + e) = acc;
}

extern "C" void kernel_launch(void* const* d_in, const int* in_sizes, int n_in,
                              void* d_out, int out_size, void* d_ws, size_t ws_size,
                              hipStream_t stream) {
    const float* x  = (const float*)d_in[0];
    const float* wq = (const float*)d_in[1];
    const float* wk = (const float*)d_in[2];
    const float* wv = (const float*)d_in[3];
    float* out = (float*)d_out;

    char* ws = (char*)d_ws;
    unsigned short* qb = (unsigned short*)(ws);               // 1,048,576 B
    unsigned short* kb = (unsigned short*)(ws + 1048576);     // 1,048,576 B
    unsigned short* vt = (unsigned short*)(ws + 2097152);     // 1,048,576 B (V^T [64][8192])
    float* O_part = (float*)(ws + 3145728);                   // 272*16384*4 = 17,825,792 B
    float* l_part = (float*)(ws + 20971520);                  // 272*256*4 = 278,528 B
    // total ws: 21,250,048 B

    proj_kernel<<<dim3(128, 3), 256, 0, stream>>>(x, wq, wk, wv, qb, kb, vt);
    attn_kernel<<<dim3(16, 32), 512, 0, stream>>>(qb, kb, vt, O_part, l_part);
    attn_reduce_kernel<<<dim3(16, 32), 256, 0, stream>>>(O_part, l_part, out);
}

// Round 18
// 118.997 us; speedup vs baseline: 1.0343x; 1.0168x over previous
//
#include <hip/hip_runtime.h>
#include <hip/hip_bf16.h>

// S=8192, D_IN=512, D_OUT=64. O = softmax(tril(QK^T)/8) @ V.
// Round 18: R15 attn+reduce byte-exact (best, 119.2us). proj: x read ONCE —
// x-frags held in registers (16 x short8 = 64 VGPR), mat-loop inside block
// re-staging the 64KB W LDS per mat (W is L2-resident; x L3 re-reads killed).
// Grid 256 x 4 waves: wave = (row-group 16, n-half 32). Staging/swizzle/
// epilogue byte-identical to R15's validated pieces.

typedef __attribute__((ext_vector_type(8))) short short8;   // 8 bf16 MFMA A/B frag
typedef __attribute__((ext_vector_type(4))) float f32x4;    // MFMA C/D frag
typedef __attribute__((ext_vector_type(4))) float f4v;
typedef __attribute__((ext_vector_type(2))) unsigned int u32x2;

__device__ inline unsigned int pk2(float a, float b) {
    union { __hip_bfloat162 h; unsigned int u; } v;
    v.h = __float22bfloat162_rn(make_float2(a, b));
    return v.u;
}
__device__ inline void gload_lds16(const void* g, void* l) {
    __builtin_amdgcn_global_load_lds(
        (const __attribute__((address_space(1))) unsigned int*)g,
        (__attribute__((address_space(3))) unsigned int*)l, 16, 0, 0);
}

// Q-blocks of 256 rows (qb in [0,32)), parts of 512 cols. np(qb) = (qb>>1)+1.
// qb = 2a+b: base(qb) = a*a + a + b*(a+1). Total slots = 272.
__device__ inline int part_base(int qb) {
    int a = qb >> 1;
    return a * a + a + (qb & 1) * (a + 1);
}

// ---------------- QKV projection: x once in registers, mat-loop ----------------
// grid 256, 256 thr (4 waves). Block: 32 x-rows. Wave w: row-group rg=w>>1
// (rows r0+rg*16..+15), n-half nh=w&1 (cols nh*32..+31).
__global__ __launch_bounds__(256) void proj_kernel(const float* __restrict__ x,
                                                   const float* __restrict__ wq,
                                                   const float* __restrict__ wk,
                                                   const float* __restrict__ wv,
                                                   unsigned short* __restrict__ qb,
                                                   unsigned short* __restrict__ kb,
                                                   unsigned short* __restrict__ vt) {
    __shared__ unsigned short lds_w[64 * 512];   // 64KB bf16 W_mat, chunk^=(row&7)
    const int tid = threadIdx.x;
    const int wave = tid >> 6, lane = tid & 63;
    const int l16 = lane & 15, quad = lane >> 4;
    const int rg = wave >> 1, nh = wave & 1;
    const int r0 = blockIdx.x * 32;
    const int rw = r0 + rg * 16;                 // wave's 16 rows

    // x-frags ONCE into registers: xf[kc] = x[rw+l16][kc*32+quad*8..+7] (bf16)
    const float* xr = x + (rw + l16) * 512 + quad * 8;
    short8 xf[16];
#pragma unroll
    for (int kc = 0; kc < 16; ++kc) {
        f4v a0 = *(const f4v*)(xr + kc * 32);
        f4v a1 = *(const f4v*)(xr + kc * 32 + 4);
        union { short8 s8; unsigned int u[4]; } av;
        av.u[0] = pk2(a0.x, a0.y); av.u[1] = pk2(a0.z, a0.w);
        av.u[2] = pk2(a1.x, a1.y); av.u[3] = pk2(a1.z, a1.w);
        xf[kc] = av.s8;
    }

    for (int mat = 0; mat < 3; ++mat) {
        const float* wm = (mat == 0) ? wq : ((mat == 1) ? wk : wv);
        if (mat > 0) __syncthreads();            // all waves done reading lds_w

        // stage + convert W_mat: 4096 chunks of 8 bf16 (R15-identical)
#pragma unroll
        for (int j = 0; j < 16; ++j) {
            const int idx = j * 256 + tid;
            const int row = idx >> 6;
            const int gc = (idx & 63) ^ (row & 7);
            f4v v0 = *(const f4v*)(wm + row * 512 + gc * 8);
            f4v v1 = *(const f4v*)(wm + row * 512 + gc * 8 + 4);
            union { short8 s8; unsigned int u[4]; } pv;
            pv.u[0] = pk2(v0.x, v0.y); pv.u[1] = pk2(v0.z, v0.w);
            pv.u[2] = pk2(v1.x, v1.y); pv.u[3] = pk2(v1.z, v1.w);
            *(short8*)(lds_w + idx * 8) = pv.s8;
        }
        __syncthreads();

        // compute: wave's 2 n-tiles (rows of W = output cols nh*32..+31)
        f32x4 acc[2] = {};
#pragma unroll
        for (int kc = 0; kc < 16; ++kc) {
#pragma unroll
            for (int c = 0; c < 2; ++c) {
                short8 b = *(const short8*)(lds_w + ((nh * 2 + c) * 16 + l16) * 512 +
                                            (((kc * 4 + quad) ^ (l16 & 7)) * 8));
                acc[c] = __builtin_amdgcn_mfma_f32_16x16x32_bf16(xf[kc], b, acc[c], 0, 0, 0);
            }
        }

        const float scale = (mat == 0) ? 0.125f : 1.0f;   // fold 1/sqrt(d_k) into Q
#pragma unroll
        for (int c = 0; c < 2; ++c)
#pragma unroll
            for (int r = 0; r < 4; ++r) {
                const int row = rw + quad * 4 + r;   // C/D: row=(lane>>4)*4+reg, col=lane&15
                const int col = nh * 32 + c * 16 + l16;
                union { __hip_bfloat16 h; unsigned short u; } hv;
                hv.h = __float2bfloat16(acc[c][r] * scale);
                if (mat == 0)       qb[row * 64 + col] = hv.u;
                else if (mat == 1)  kb[row * 64 + col] = hv.u;
                else                vt[col * 8192 + row] = hv.u;   // V^T [64][8192]
            }
    }
}

// ---------------- staged split-K flash attention, 256-row Q-blocks (R15 byte-exact) ----------------
// grid (16, 32), 512 thr (8 waves). blockIdx.y = qb (256 rows), x = part (512 cols).
__global__ __launch_bounds__(512) void attn_kernel(const unsigned short* __restrict__ qbuf,
                                                   const unsigned short* __restrict__ kbuf,
                                                   const unsigned short* __restrict__ vt,
                                                   float* __restrict__ O_part,
                                                   float* __restrict__ l_part) {
    const int qb_i = blockIdx.y;
    const int part = blockIdx.x;
    const int a = qb_i >> 1;
    if (part > a) return;                         // np = a+1; block-uniform exit

    __shared__ unsigned short lds_k[64 * 64];     // [row][64], chunk^=(row&7)  8KB
    __shared__ unsigned short lds_v[64 * 64];     // V^T tile [dim][64]         8KB
    __shared__ unsigned short lds_p[8][32 * 72];  // per-wave P, stride 72      36KB

    const int tid = threadIdx.x;
    const int wave = tid >> 6, lane = tid & 63;
    const int l16 = lane & 15, quad = lane >> 4;
    const int q0 = qb_i * 256;
    const int q0w = q0 + wave * 32;
    const int c0 = part * 512;
    const int cend = min(c0 + 512, q0 + 256);     // 64-aligned
    const int ntiles = (cend - c0) >> 6;          // 4 or 8
    unsigned short* lp = lds_p[wave];

    f32x4 o[2][4] = {};
    float ls[2] = {0.f, 0.f};

    short8 qf[2][2];
#pragma unroll
    for (int cg = 0; cg < 2; ++cg)
#pragma unroll
        for (int kg = 0; kg < 2; ++kg)
            qf[cg][kg] = *(const short8*)(qbuf + (q0w + cg * 16 + l16) * 64 + kg * 32 + quad * 8);

    const int sidx = tid;
    const int srow = sidx >> 3;
    const int scc = (sidx & 7) ^ (srow & 7);

    for (int it = 0; it < ntiles; ++it) {
        const int kc0 = c0 + it * 64;
        gload_lds16(kbuf + (kc0 + srow) * 64 + scc * 8, lds_k + sidx * 8);
        gload_lds16(vt + srow * 8192 + kc0 + scc * 8,   lds_v + sidx * 8);
        __syncthreads();

        if (kc0 <= q0w + 31) {                    // wave-uniform compute guard
            short8 af[4][2], vf[4][2];
#pragma unroll
            for (int rg = 0; rg < 4; ++rg)
#pragma unroll
                for (int kg = 0; kg < 2; ++kg)
                    af[rg][kg] = *(const short8*)(lds_k + (rg * 16 + l16) * 64 +
                                                  (((kg * 4 + quad) ^ (l16 & 7)) * 8));
#pragma unroll
            for (int ng = 0; ng < 4; ++ng)
#pragma unroll
                for (int kg = 0; kg < 2; ++kg)
                    vf[ng][kg] = *(const short8*)(lds_v + (ng * 16 + l16) * 64 +
                                                  (((kg * 4 + quad) ^ (l16 & 7)) * 8));

            // S^T = K Q^T: row=K-col kc0+rg*16+quad*4+r, col=Q-row q0w+cg*16+l16
            f32x4 st[4][2];
#pragma unroll
            for (int rg = 0; rg < 4; ++rg)
#pragma unroll
                for (int cg = 0; cg < 2; ++cg) {
                    f32x4 z = {};
                    z          = __builtin_amdgcn_mfma_f32_16x16x32_bf16(af[rg][0], qf[cg][0], z, 0, 0, 0);
                    st[rg][cg] = __builtin_amdgcn_mfma_f32_16x16x32_bf16(af[rg][1], qf[cg][1], z, 0, 0, 0);
                }

            if (kc0 + 63 > q0w) {                 // diagonal tiles only
#pragma unroll
                for (int rg = 0; rg < 4; ++rg)
#pragma unroll
                    for (int cg = 0; cg < 2; ++cg)
#pragma unroll
                        for (int r = 0; r < 4; ++r) {
                            const int kcol = kc0 + rg * 16 + quad * 4 + r;
                            const int qrow = q0w + cg * 16 + l16;
                            if (kcol > qrow) st[rg][cg][r] = -3.0e38f;
                        }
            }

            // p = exp(s), no max subtraction (r3-validated)
#pragma unroll
            for (int rg = 0; rg < 4; ++rg)
#pragma unroll
                for (int cg = 0; cg < 2; ++cg)
#pragma unroll
                    for (int r = 0; r < 4; ++r) {
                        const float p = __expf(st[rg][cg][r]);
                        st[rg][cg][r] = p;
                        ls[cg] += p;
                    }

            // P -> per-wave LDS, stride 72 (wave-synchronous)
#pragma unroll
            for (int rg = 0; rg < 4; ++rg)
#pragma unroll
                for (int cg = 0; cg < 2; ++cg) {
                    u32x2 w;
                    w.x = pk2(st[rg][cg][0], st[rg][cg][1]);
                    w.y = pk2(st[rg][cg][2], st[rg][cg][3]);
                    *(u32x2*)(lp + (cg * 16 + l16) * 72 + rg * 16 + quad * 4) = w;
                }
            asm volatile("s_waitcnt lgkmcnt(0)" ::: "memory");
            short8 pa[2][2];
#pragma unroll
            for (int mg = 0; mg < 2; ++mg)
#pragma unroll
                for (int kg = 0; kg < 2; ++kg)
                    pa[mg][kg] = *(const short8*)(lp + (mg * 16 + l16) * 72 + kg * 32 + quad * 8);

#pragma unroll
            for (int mg = 0; mg < 2; ++mg)
#pragma unroll
                for (int ng = 0; ng < 4; ++ng) {
                    o[mg][ng] = __builtin_amdgcn_mfma_f32_16x16x32_bf16(pa[mg][0], vf[ng][0], o[mg][ng], 0, 0, 0);
                    o[mg][ng] = __builtin_amdgcn_mfma_f32_16x16x32_bf16(pa[mg][1], vf[ng][1], o[mg][ng], 0, 0, 0);
                }
        }
        __syncthreads();
    }

#pragma unroll
    for (int cg = 0; cg < 2; ++cg) {
        ls[cg] += __shfl_xor(ls[cg], 16, 64);
        ls[cg] += __shfl_xor(ls[cg], 32, 64);
    }

    const int slot = part_base(qb_i) + part;
    float* Op = O_part + (size_t)slot * 16384;    // 256 rows x 64 cols
#pragma unroll
    for (int mg = 0; mg < 2; ++mg)
#pragma unroll
        for (int ng = 0; ng < 4; ++ng)
#pragma unroll
            for (int r = 0; r < 4; ++r)
                __builtin_nontemporal_store(o[mg][ng][r],
                    Op + (wave * 32 + mg * 16 + quad * 4 + r) * 64 + ng * 16 + l16);
    if (quad == 0) {
#pragma unroll
        for (int cg = 0; cg < 2; ++cg)
            __builtin_nontemporal_store(ls[cg],
                l_part + slot * 256 + wave * 32 + cg * 16 + l16);
    }
}

// ---------------- combine: parallel sum, latency-hidden (R15 byte-exact) ----------------
__global__ __launch_bounds__(256) void attn_reduce_kernel(const float* __restrict__ O_part,
                                                          const float* __restrict__ l_part,
                                                          float* __restrict__ out) {
    __shared__ float Ls[16];
    const int qb_i = blockIdx.y;
    const int c = blockIdx.x;
    const int t = threadIdx.x;
    const int np = (qb_i >> 1) + 1;
    const int base = part_base(qb_i);

    if (t < 16) {
        float s = 0.0f;
        for (int p = 0; p < np; ++p)
            s += l_part[(base + p) * 256 + c * 16 + t];
        Ls[t] = s;
    }
    __syncthreads();

    const int e = c * 1024 + t * 4;               // element within slot / out tile
    const float* src = O_part + (size_t)base * 16384 + e;

    f4v a0 = {0.f, 0.f, 0.f, 0.f}, a1 = a0, a2 = a0, a3 = a0;
    int p = 0;
    for (; p + 4 <= np; p += 4) {
        a0 += *(const f4v*)(src + (size_t)(p    ) * 16384);
        a1 += *(const f4v*)(src + (size_t)(p + 1) * 16384);
        a2 += *(const f4v*)(src + (size_t)(p + 2) * 16384);
        a3 += *(const f4v*)(src + (size_t)(p + 3) * 16384);
    }
    for (; p < np; ++p)
        a0 += *(const f4v*)(src + (size_t)p * 16384);

    f4v acc = (a0 + a1) + (a2 + a3);
    acc *= (1.0f / Ls[t >> 4]);
    *(f4v*)(out + (size_t)qb_i * 16384 + e) = acc;
}

extern "C" void kernel_launch(void* const* d_in, const int* in_sizes, int n_in,
                              void* d_out, int out_size, void* d_ws, size_t ws_size,
                              hipStream_t stream) {
    const float* x  = (const float*)d_in[0];
    const float* wq = (const float*)d_in[1];
    const float* wk = (const float*)d_in[2];
    const float* wv = (const float*)d_in[3];
    float* out = (float*)d_out;

    char* ws = (char*)d_ws;
    unsigned short* qb = (unsigned short*)(ws);               // 1,048,576 B
    unsigned short* kb = (unsigned short*)(ws + 1048576);     // 1,048,576 B
    unsigned short* vt = (unsigned short*)(ws + 2097152);     // 1,048,576 B (V^T [64][8192])
    float* O_part = (float*)(ws + 3145728);                   // 272*16384*4 = 17,825,792 B
    float* l_part = (float*)(ws + 20971520);                  // 272*256*4 = 278,528 B
    // total ws: 21,250,048 B

    proj_kernel<<<256, 256, 0, stream>>>(x, wq, wk, wv, qb, kb, vt);
    attn_kernel<<<dim3(16, 32), 512, 0, stream>>>(qb, kb, vt, O_part, l_part);
    attn_reduce_kernel<<<dim3(16, 32), 256, 0, stream>>>(O_part, l_part, out);
}